// Round 6
// baseline (386.763 us; speedup 1.0000x reference)
//
#include <hip/hip_runtime.h>

#define N_NODES 100000
#define D 128
#define N_EDGES 640000
#define TOT_EDGES (3 * N_EDGES)   // 1,920,000

#define NB   256                  // buckets (node ranges)
#define NPB  391                  // nodes per bucket (256*391 >= 100000)
#define BCAP 9216                 // record capacity per bucket (mean 7500, +20 sigma)
#define OVF_CAP 65536
#define EPB  3072                 // edges per binA block
#define BINA_BLOCKS (TOT_EDGES / EPB)   // 625
#define EPT  (EPB / 256)                // 12 edges per thread

// ---------------- fast-path ws layout (bytes) ----------------
#define WS_OVFCNT 0
#define WS_BCUR   64                         // int, stride 16 ints (64B/bucket)
#define WS_BBASE  16448                      // int[256]
#define WS_BNUM   17472                      // int[256]
#define WS_OVF    18496                      // int4[OVF_CAP], 1 MB
#define WS_TMP    1067072                    // int2[NB*BCAP], 18.9 MB
#define WS_FREC   19941440                   // int2[TOT_EDGES], 15.36 MB
#define WS_XB     35301440                   // ushort[N_NODES*D] bf16, 25.6 MB
#define WS_TOTAL_FAST 60901440

__device__ __forceinline__ void load_r(const float* z0, const float* z1,
                                       const float* z2, const float* z3,
                                       float& r0, float& r1, float& r2, float& r3) {
    r0 = fmaxf(z0[0], 0.0f);
    r1 = fmaxf(z1[0], 0.0f);
    r2 = fmaxf(z2[0], 0.0f);
    r3 = fmaxf(z3[0], 0.0f);
    float inv = 1.0f / (r0 + r1 + r2 + r3 + 1e-6f);
    r0 *= inv; r1 *= inv; r2 *= inv; r3 *= inv;
}

__device__ __forceinline__ unsigned short bf16rn(float f) {
    unsigned int u = __float_as_uint(f);
    u += 0x7FFFu + ((u >> 16) & 1u);   // round to nearest even
    return (unsigned short)(u >> 16);
}

// ---- cast x -> bf16 copy (halves gather traffic) ---------------------------
__global__ void cast_kernel(const float* __restrict__ x, ushort* __restrict__ xb) {
    int i = blockIdx.x * 256 + threadIdx.x;
    if (i >= N_NODES * D / 4) return;
    float4 v = ((const float4*)x)[i];
    ushort4 h;
    h.x = bf16rn(v.x); h.y = bf16rn(v.y); h.z = bf16rn(v.z); h.w = bf16rn(v.w);
    ((ushort4*)xb)[i] = h;
}

// ---------------------------------------------------------------------------
// binA: LDS-aggregated binning of all edges into 256 node-range buckets.
// tmp rec: x = dst(17) | set<<17 (2) | local<<19 (9), y = f32 scale.
// ---------------------------------------------------------------------------
__global__ void binA_kernel(const int* __restrict__ ei1, const float* __restrict__ w1,
                            const int* __restrict__ ei2, const float* __restrict__ w2,
                            const int* __restrict__ ei3, const float* __restrict__ w3,
                            const float* __restrict__ z0, const float* __restrict__ z1,
                            const float* __restrict__ z2, const float* __restrict__ z3,
                            int* __restrict__ bcur, int* __restrict__ ovf_count,
                            int4* __restrict__ ovf, int2* __restrict__ tmp) {
    __shared__ int hist[NB];
    __shared__ int base[NB];
    int t = threadIdx.x;
    hist[t] = 0;
    __syncthreads();

    int e0 = blockIdx.x * EPB;
    int rank[EPT];
    int bkt[EPT];

    for (int k = 0; k < EPT; ++k) {
        int e = e0 + t + k * 256;
        int set = e / N_EDGES;
        int idx = e - set * N_EDGES;
        const int* ei = (set == 0) ? ei1 : (set == 1) ? ei2 : ei3;
        int src = ei[idx];
        int b = src / NPB;
        bkt[k]  = b;
        rank[k] = atomicAdd(&hist[b], 1);
    }
    __syncthreads();

    {
        int h = hist[t];
        base[t] = h ? atomicAdd(&bcur[t * 16], h) : 0;
    }
    __syncthreads();

    float r0, r1, r2, r3;
    load_r(z0, z1, z2, z3, r0, r1, r2, r3);

    for (int k = 0; k < EPT; ++k) {
        int e = e0 + t + k * 256;
        int set = e / N_EDGES;
        int idx = e - set * N_EDGES;
        const int* ei;  const float* w;
        if      (set == 0) { ei = ei1; w = w1; }
        else if (set == 1) { ei = ei2; w = w2; }
        else               { ei = ei3; w = w3; }
        int src = ei[idx];
        int dst = ei[N_EDGES + idx];
        float rk = (set == 0) ? r1 : (set == 1) ? r2 : r3;
        float scale = rk * w[idx];
        int b = bkt[k];
        int local = src - b * NPB;
        int pos = base[b] + rank[k];
        int rx = dst | (set << 17) | (local << 19);
        if (pos < BCAP) {
            tmp[(size_t)b * BCAP + pos] = make_int2(rx, __float_as_int(scale));
        } else {
            int o = atomicAdd(ovf_count, 1);
            if (o < OVF_CAP) ovf[o] = make_int4(src, dst | (set << 17),
                                                __float_as_int(scale), 0);
        }
    }
}

// scanB: exclusive scan of (clamped) bucket counts -> global bucket bases.
__global__ void scanB_kernel(const int* __restrict__ bcur,
                             int* __restrict__ bbase, int* __restrict__ bnum) {
    __shared__ int s[NB];
    int t = threadIdx.x;
    int n = bcur[t * 16];
    if (n > BCAP) n = BCAP;
    bnum[t] = n;
    s[t] = n;
    __syncthreads();
    for (int off = 1; off < NB; off <<= 1) {
        int v = (t >= off) ? s[t - off] : 0;
        __syncthreads();
        s[t] += v;
        __syncthreads();
    }
    bbase[t] = s[t] - n;
}

// ---------------------------------------------------------------------------
// bucket_kernel: fused binB + gather. One 1024-thread block per bucket.
// Phase 1-3: LDS degree count + scan, scatter sorted recs into frecs (the
//   73 KB window stays in this XCD's L2 — written and re-read locally).
// Phase 4: 16 waves gather the bucket's nodes from the bf16 copy of x;
//   self term from exact fp32 x; roll handled by shift-separated accumulators
//   + one end-of-loop lane rotation.
// ---------------------------------------------------------------------------
__global__ __launch_bounds__(1024) void bucket_kernel(
        const float* __restrict__ x, const ushort* __restrict__ xb,
        const int2* __restrict__ tmp,
        const int* __restrict__ bbase, const int* __restrict__ bnum,
        int2* __restrict__ frecs,
        const float* __restrict__ z0, const float* __restrict__ z1,
        const float* __restrict__ z2, const float* __restrict__ z3,
        float* __restrict__ out) {
    __shared__ int d[512];
    __shared__ int s[512];
    __shared__ int cur[512];
    int b = blockIdx.x;
    int t = threadIdx.x;
    int n = bnum[b];
    int gbase = bbase[b];
    const int2* bucket = tmp + (size_t)b * BCAP;

    if (t < 512) d[t] = 0;
    __syncthreads();
    for (int i = t; i < n; i += 1024)
        atomicAdd(&d[(bucket[i].x >> 19) & 0x1FF], 1);
    __syncthreads();
    if (t < 512) s[t] = d[t];
    __syncthreads();
    for (int off = 1; off < 512; off <<= 1) {
        int v = 0;
        if (t < 512 && t >= off) v = s[t - off];
        __syncthreads();
        if (t < 512) s[t] += v;
        __syncthreads();
    }
    if (t < 512) cur[t] = s[t] - d[t];      // exclusive prefix
    __syncthreads();
    for (int i = t; i < n; i += 1024) {
        int2 rec = bucket[i];
        int pos = atomicAdd(&cur[(rec.x >> 19) & 0x1FF], 1);
        frecs[gbase + pos] = rec;
    }
    __syncthreads();
    // now cur[l] = inclusive end; beg = cur[l] - d[l]

    float r0, r1, r2, r3;
    load_r(z0, z1, z2, z3, r0, r1, r2, r3);

    int wave = t >> 6;
    int lane = t & 63;
    int prev = (lane + 63) & 63;

    for (int l = wave; l < NPB; l += 16) {
        int node = b * NPB + l;
        if (node >= N_NODES) break;         // only block 255; wave-uniform
        int endp = cur[l];
        int beg  = endp - d[l];

        float2 xv = ((const float2*)(x + (size_t)node * D))[lane];
        float2 a0 = {0.f, 0.f}, a1 = {0.f, 0.f}, a2 = {0.f, 0.f};

        int j = beg;
        for (; j + 1 < endp; j += 2) {
            int2 ra = frecs[gbase + j];
            int2 rb = frecs[gbase + j + 1];
            unsigned int va = ((const unsigned int*)(xb + (size_t)(ra.x & 0x1FFFF) * D))[lane];
            unsigned int vb = ((const unsigned int*)(xb + (size_t)(rb.x & 0x1FFFF) * D))[lane];
            int sha = (ra.x >> 17) & 3, shb = (rb.x >> 17) & 3;
            float sca = __int_as_float(ra.y);
            float scb = __int_as_float(rb.y);
            float ax = __uint_as_float(va << 16);
            float ay = __uint_as_float(va & 0xFFFF0000u);
            float bx = __uint_as_float(vb << 16);
            float by = __uint_as_float(vb & 0xFFFF0000u);
            if      (sha == 0) { a0.x += sca * ax; a0.y += sca * ay; }
            else if (sha == 1) { a1.x += sca * ax; a1.y += sca * ay; }
            else               { a2.x += sca * ax; a2.y += sca * ay; }
            if      (shb == 0) { a0.x += scb * bx; a0.y += scb * by; }
            else if (shb == 1) { a1.x += scb * bx; a1.y += scb * by; }
            else               { a2.x += scb * bx; a2.y += scb * by; }
        }
        if (j < endp) {
            int2 rec = frecs[gbase + j];
            unsigned int vv = ((const unsigned int*)(xb + (size_t)(rec.x & 0x1FFFF) * D))[lane];
            int sh = (rec.x >> 17) & 3;
            float sc = __int_as_float(rec.y);
            float vx = __uint_as_float(vv << 16);
            float vy = __uint_as_float(vv & 0xFFFF0000u);
            if      (sh == 0) { a0.x += sc * vx; a0.y += sc * vy; }
            else if (sh == 1) { a1.x += sc * vx; a1.y += sc * vy; }
            else               { a2.x += sc * vx; a2.y += sc * vy; }
        }

        // out[c] = r0*x[c] + a0[c] + a1[(c-1)&127] + a2[(c-2)&127]
        float r1y = __shfl(a1.y, prev);
        float r2x = __shfl(a2.x, prev);
        float r2y = __shfl(a2.y, prev);
        float2 o;
        o.x = r0 * xv.x + a0.x + r1y  + r2x;
        o.y = r0 * xv.y + a0.y + a1.x + r2y;
        ((float2*)(out + (size_t)node * D))[lane] = o;
    }
}

// overflow cleanup: wave per record, atomic add (expected ~0 records)
__global__ void ovf_kernel(const float* __restrict__ x,
                           const int* __restrict__ ovf_count,
                           const int4* __restrict__ ovf,
                           float* __restrict__ out) {
    int total_waves = (gridDim.x * blockDim.x) >> 6;
    int gw   = (blockIdx.x * blockDim.x + threadIdx.x) >> 6;
    int lane = threadIdx.x & 63;
    int n = *ovf_count;
    if (n > OVF_CAP) n = OVF_CAP;
    for (int r = gw; r < n; r += total_waves) {
        int4 rec = ovf[r];
        int src = rec.x;
        int dst = rec.y & 0x1FFFF;
        int sh  = (rec.y >> 17) & 3;
        float sc = __int_as_float(rec.z);
        const float* xr = x + (size_t)dst * D;
        float* orow = out + (size_t)src * D;
        int c0 = 2 * lane, c1 = 2 * lane + 1;
        atomicAdd(&orow[c0], sc * xr[(c0 - sh) & 127]);
        atomicAdd(&orow[c1], sc * xr[(c1 - sh) & 127]);
    }
}

// ===========================================================================
// MID TIER fallback (R3 exact-CSR path), used if ws too small for fast path.
// ===========================================================================
#define SCAN_BLOCKS ((N_NODES + 255) / 256)   // 391
#define WS_COUNTS   0
#define WS_OFFSETS  400000
#define WS_CURSORS  800008
#define WS_BSUM     1200008
#define WS_BPRE     1201576
#define WS_RECS     1203144
#define WS_NEEDED_MID (WS_RECS + (size_t)TOT_EDGES * 8)

__global__ void hist_kernel(const int* __restrict__ ei1, const int* __restrict__ ei2,
                            const int* __restrict__ ei3, int* __restrict__ counts) {
    int e = blockIdx.x * blockDim.x + threadIdx.x;
    if (e >= TOT_EDGES) return;
    int set = e / N_EDGES;
    int idx = e - set * N_EDGES;
    const int* ei = (set == 0) ? ei1 : (set == 1) ? ei2 : ei3;
    atomicAdd(&counts[ei[idx]], 1);
}

__global__ void scan1_kernel(const int* __restrict__ counts,
                             int* __restrict__ offsets, int* __restrict__ bsum) {
    __shared__ int s[256];
    int t = threadIdx.x;
    int i = blockIdx.x * 256 + t;
    int v = (i < N_NODES) ? counts[i] : 0;
    s[t] = v;
    __syncthreads();
    for (int off = 1; off < 256; off <<= 1) {
        int u = (t >= off) ? s[t - off] : 0;
        __syncthreads();
        s[t] += u;
        __syncthreads();
    }
    if (i < N_NODES) offsets[i] = s[t] - v;
    if (t == 255) bsum[blockIdx.x] = s[255];
}

__global__ void scan2_kernel(const int* __restrict__ bsum, int* __restrict__ bpre) {
    __shared__ int s[512];
    int t = threadIdx.x;
    int v = (t < SCAN_BLOCKS) ? bsum[t] : 0;
    s[t] = v;
    __syncthreads();
    for (int off = 1; off < 512; off <<= 1) {
        int u = (t >= off) ? s[t - off] : 0;
        __syncthreads();
        s[t] += u;
        __syncthreads();
    }
    if (t < SCAN_BLOCKS) bpre[t] = s[t] - v;
}

__global__ void scan3_kernel(int* __restrict__ offsets, const int* __restrict__ bpre,
                             int* __restrict__ cursors) {
    int i = blockIdx.x * 256 + threadIdx.x;
    if (i < N_NODES) {
        int v = offsets[i] + bpre[blockIdx.x];
        offsets[i] = v;
        cursors[i] = v;
    }
    if (i == 0) offsets[N_NODES] = TOT_EDGES;
}

__global__ void fill_kernel(const int* __restrict__ ei1, const float* __restrict__ w1,
                            const int* __restrict__ ei2, const float* __restrict__ w2,
                            const int* __restrict__ ei3, const float* __restrict__ w3,
                            const float* __restrict__ z0, const float* __restrict__ z1,
                            const float* __restrict__ z2, const float* __restrict__ z3,
                            int* __restrict__ cursors, int2* __restrict__ recs) {
    int e = blockIdx.x * blockDim.x + threadIdx.x;
    if (e >= TOT_EDGES) return;
    int set = e / N_EDGES;
    int idx = e - set * N_EDGES;
    const int* ei;  const float* w;
    if      (set == 0) { ei = ei1; w = w1; }
    else if (set == 1) { ei = ei2; w = w2; }
    else               { ei = ei3; w = w3; }
    float r0, r1, r2, r3;
    load_r(z0, z1, z2, z3, r0, r1, r2, r3);
    float rk = (set == 0) ? r1 : (set == 1) ? r2 : r3;
    int src = ei[idx];
    int dst = ei[N_EDGES + idx];
    float scale = rk * w[idx];
    int pos = atomicAdd(&cursors[src], 1);
    recs[pos] = make_int2(dst | (set << 17), __float_as_int(scale));
}

__global__ void gatherd_kernel(const float* __restrict__ x,
                               const int* __restrict__ offsets,
                               const int2* __restrict__ recs,
                               const float* __restrict__ z0, const float* __restrict__ z1,
                               const float* __restrict__ z2, const float* __restrict__ z3,
                               float* __restrict__ out) {
    int wid  = (blockIdx.x * blockDim.x + threadIdx.x) >> 6;
    int lane = threadIdx.x & 63;
    if (wid >= N_NODES) return;
    float r0, r1, r2, r3;
    load_r(z0, z1, z2, z3, r0, r1, r2, r3);
    float2 xv = ((const float2*)(x + (size_t)wid * D))[lane];
    int beg = offsets[wid];
    int end = offsets[wid + 1];
    float2 a0 = {0.f, 0.f}, a1 = {0.f, 0.f}, a2 = {0.f, 0.f};
    for (int j = beg; j < end; ++j) {
        int2 rec = recs[j];
        float2 v = ((const float2*)(x + (size_t)(rec.x & 0x1FFFF) * D))[lane];
        int sh = (rec.x >> 17) & 3;
        float sc = __int_as_float(rec.y);
        if      (sh == 0) { a0.x += sc * v.x; a0.y += sc * v.y; }
        else if (sh == 1) { a1.x += sc * v.x; a1.y += sc * v.y; }
        else               { a2.x += sc * v.x; a2.y += sc * v.y; }
    }
    int prev = (lane + 63) & 63;
    float r1y = __shfl(a1.y, prev);
    float r2x = __shfl(a2.x, prev);
    float r2y = __shfl(a2.y, prev);
    float2 o;
    o.x = r0 * xv.x + a0.x + r1y  + r2x;
    o.y = r0 * xv.y + a0.y + a1.x + r2y;
    ((float2*)(out + (size_t)wid * D))[lane] = o;
}

extern "C" void kernel_launch(void* const* d_in, const int* in_sizes, int n_in,
                              void* d_out, int out_size, void* d_ws, size_t ws_size,
                              hipStream_t stream) {
    const float* x   = (const float*)d_in[0];
    const int*   ei1 = (const int*)  d_in[1];
    const float* w1  = (const float*)d_in[2];
    const int*   ei2 = (const int*)  d_in[3];
    const float* w2  = (const float*)d_in[4];
    const int*   ei3 = (const int*)  d_in[5];
    const float* w3  = (const float*)d_in[6];
    const float* z0  = (const float*)d_in[7];
    const float* z1  = (const float*)d_in[8];
    const float* z2  = (const float*)d_in[9];
    const float* z3  = (const float*)d_in[10];
    float* out = (float*)d_out;
    char* wsc = (char*)d_ws;

    if (ws_size >= WS_TOTAL_FAST) {
        int*    ovf_count = (int*)   (wsc + WS_OVFCNT);
        int*    bcur      = (int*)   (wsc + WS_BCUR);
        int*    bbase     = (int*)   (wsc + WS_BBASE);
        int*    bnum      = (int*)   (wsc + WS_BNUM);
        int4*   ovf       = (int4*)  (wsc + WS_OVF);
        int2*   tmp       = (int2*)  (wsc + WS_TMP);
        int2*   frecs     = (int2*)  (wsc + WS_FREC);
        ushort* xb        = (ushort*)(wsc + WS_XB);

        hipMemsetAsync(wsc, 0, WS_BBASE, stream);   // ovf_count + bucket cursors
        cast_kernel<<<(N_NODES * D / 4 + 255) / 256, 256, 0, stream>>>(x, xb);
        binA_kernel<<<BINA_BLOCKS, 256, 0, stream>>>(ei1, w1, ei2, w2, ei3, w3,
                                                     z0, z1, z2, z3,
                                                     bcur, ovf_count, ovf, tmp);
        scanB_kernel<<<1, NB, 0, stream>>>(bcur, bbase, bnum);
        bucket_kernel<<<NB, 1024, 0, stream>>>(x, xb, tmp, bbase, bnum, frecs,
                                               z0, z1, z2, z3, out);
        ovf_kernel<<<128, 256, 0, stream>>>(x, ovf_count, ovf, out);
    } else {
        int*  counts  = (int*) (wsc + WS_COUNTS);
        int*  offsets = (int*) (wsc + WS_OFFSETS);
        int*  cursors = (int*) (wsc + WS_CURSORS);
        int*  bsum    = (int*) (wsc + WS_BSUM);
        int*  bpre    = (int*) (wsc + WS_BPRE);
        int2* recs    = (int2*)(wsc + WS_RECS);

        hipMemsetAsync(counts, 0, N_NODES * sizeof(int), stream);
        hist_kernel<<<TOT_EDGES / 256, 256, 0, stream>>>(ei1, ei2, ei3, counts);
        scan1_kernel<<<SCAN_BLOCKS, 256, 0, stream>>>(counts, offsets, bsum);
        scan2_kernel<<<1, 512, 0, stream>>>(bsum, bpre);
        scan3_kernel<<<SCAN_BLOCKS, 256, 0, stream>>>(offsets, bpre, cursors);
        fill_kernel<<<TOT_EDGES / 256, 256, 0, stream>>>(ei1, w1, ei2, w2, ei3, w3,
                                                         z0, z1, z2, z3, cursors, recs);
        gatherd_kernel<<<(N_NODES * 64 + 255) / 256, 256, 0, stream>>>(x, offsets, recs,
                                                                       z0, z1, z2, z3, out);
    }
}

// Round 7
// 300.979 us; speedup vs baseline: 1.2850x; 1.2850x over previous
//
#include <hip/hip_runtime.h>

#define N_NODES 100000
#define D 128
#define N_EDGES 640000
#define TOT_EDGES (3 * N_EDGES)   // 1,920,000

#define NB   256                  // buckets (node ranges)
#define NPB  391                  // nodes per bucket (256*391 >= 100000)
#define BCAP 9216                 // record capacity per bucket (mean 7500, +20 sigma)
#define OVF_CAP 16384
#define EPB  3072                 // edges per binA block
#define BINA_BLOCKS (TOT_EDGES / EPB)   // 625
#define EPT  (EPB / 256)                // 12 edges per thread

// ---------------- fast-path ws layout (bytes); total 60,515,016 ------------
// (must stay <= 60,901,440 — proven available in R6)
#define WS_OVFCNT 0
#define WS_BCUR   64                         // int, stride 16 ints (64B/bucket)
#define WS_BBASE  16448                      // int[256]
#define WS_BNUM   17472                      // int[256]
#define WS_OVF    18496                      // int4[OVF_CAP], 256 KB
#define WS_TMP    280640                     // int2[NB*BCAP], 18.87 MB
#define WS_FREC   19155008                   // int2[TOT_EDGES], 15.36 MB
#define WS_OFFS   34515008                   // int[N_NODES+1]
#define WS_XB     34915016                   // ushort[N_NODES*D] bf16, 25.6 MB
#define WS_TOTAL_FAST 60515016

__device__ __forceinline__ void load_r(const float* z0, const float* z1,
                                       const float* z2, const float* z3,
                                       float& r0, float& r1, float& r2, float& r3) {
    r0 = fmaxf(z0[0], 0.0f);
    r1 = fmaxf(z1[0], 0.0f);
    r2 = fmaxf(z2[0], 0.0f);
    r3 = fmaxf(z3[0], 0.0f);
    float inv = 1.0f / (r0 + r1 + r2 + r3 + 1e-6f);
    r0 *= inv; r1 *= inv; r2 *= inv; r3 *= inv;
}

__device__ __forceinline__ unsigned short bf16rn(float f) {
    unsigned int u = __float_as_uint(f);
    u += 0x7FFFu + ((u >> 16) & 1u);   // round to nearest even
    return (unsigned short)(u >> 16);
}

// ---- cast x -> bf16 copy (halves gather traffic) ---------------------------
__global__ void cast_kernel(const float* __restrict__ x, ushort* __restrict__ xb) {
    int i = blockIdx.x * 256 + threadIdx.x;
    if (i >= N_NODES * D / 4) return;
    float4 v = ((const float4*)x)[i];
    ushort4 h;
    h.x = bf16rn(v.x); h.y = bf16rn(v.y); h.z = bf16rn(v.z); h.w = bf16rn(v.w);
    ((ushort4*)xb)[i] = h;
}

// ---------------------------------------------------------------------------
// binA: LDS-aggregated binning of all edges into 256 node-range buckets.
// tmp rec: x = dst(17) | set<<17 (2) | local<<19 (9), y = f32 scale.
// ---------------------------------------------------------------------------
__global__ void binA_kernel(const int* __restrict__ ei1, const float* __restrict__ w1,
                            const int* __restrict__ ei2, const float* __restrict__ w2,
                            const int* __restrict__ ei3, const float* __restrict__ w3,
                            const float* __restrict__ z0, const float* __restrict__ z1,
                            const float* __restrict__ z2, const float* __restrict__ z3,
                            int* __restrict__ bcur, int* __restrict__ ovf_count,
                            int4* __restrict__ ovf, int2* __restrict__ tmp) {
    __shared__ int hist[NB];
    __shared__ int base[NB];
    int t = threadIdx.x;
    hist[t] = 0;
    __syncthreads();

    int e0 = blockIdx.x * EPB;
    int rank[EPT];
    int bkt[EPT];

    for (int k = 0; k < EPT; ++k) {
        int e = e0 + t + k * 256;
        int set = e / N_EDGES;
        int idx = e - set * N_EDGES;
        const int* ei = (set == 0) ? ei1 : (set == 1) ? ei2 : ei3;
        int src = ei[idx];
        int b = src / NPB;
        bkt[k]  = b;
        rank[k] = atomicAdd(&hist[b], 1);
    }
    __syncthreads();

    {
        int h = hist[t];
        base[t] = h ? atomicAdd(&bcur[t * 16], h) : 0;
    }
    __syncthreads();

    float r0, r1, r2, r3;
    load_r(z0, z1, z2, z3, r0, r1, r2, r3);

    for (int k = 0; k < EPT; ++k) {
        int e = e0 + t + k * 256;
        int set = e / N_EDGES;
        int idx = e - set * N_EDGES;
        const int* ei;  const float* w;
        if      (set == 0) { ei = ei1; w = w1; }
        else if (set == 1) { ei = ei2; w = w2; }
        else               { ei = ei3; w = w3; }
        int src = ei[idx];
        int dst = ei[N_EDGES + idx];
        float rk = (set == 0) ? r1 : (set == 1) ? r2 : r3;
        float scale = rk * w[idx];
        int b = bkt[k];
        int local = src - b * NPB;
        int pos = base[b] + rank[k];
        int rx = dst | (set << 17) | (local << 19);
        if (pos < BCAP) {
            tmp[(size_t)b * BCAP + pos] = make_int2(rx, __float_as_int(scale));
        } else {
            int o = atomicAdd(ovf_count, 1);
            if (o < OVF_CAP) ovf[o] = make_int4(src, dst | (set << 17),
                                                __float_as_int(scale), 0);
        }
    }
}

// scanB: exclusive scan of (clamped) bucket counts -> global bucket bases.
__global__ void scanB_kernel(const int* __restrict__ bcur,
                             int* __restrict__ bbase, int* __restrict__ bnum,
                             int* __restrict__ offsets) {
    __shared__ int s[NB];
    int t = threadIdx.x;
    int n = bcur[t * 16];
    if (n > BCAP) n = BCAP;
    bnum[t] = n;
    s[t] = n;
    __syncthreads();
    for (int off = 1; off < NB; off <<= 1) {
        int v = (t >= off) ? s[t - off] : 0;
        __syncthreads();
        s[t] += v;
        __syncthreads();
    }
    bbase[t] = s[t] - n;
    if (t == NB - 1) offsets[N_NODES] = s[t];
}

// binB: per-bucket local CSR (LDS degree count + scan), emit dense sorted recs
// + per-node offsets. Scatter stays inside the bucket's ~73KB L2-hot window.
__global__ void binB_kernel(const int2* __restrict__ tmp,
                            const int* __restrict__ bbase, const int* __restrict__ bnum,
                            int2* __restrict__ frecs, int* __restrict__ offsets) {
    __shared__ int d[512];
    __shared__ int s[512];
    __shared__ int cur[NPB];
    int b = blockIdx.x;
    int t = threadIdx.x;
    int n = bnum[b];
    int gbase = bbase[b];

    d[t] = 0; d[t + 256] = 0;
    __syncthreads();
    for (int i = t; i < n; i += 256) {
        int rx = tmp[(size_t)b * BCAP + i].x;
        atomicAdd(&d[(rx >> 19) & 0x1FF], 1);
    }
    __syncthreads();
    s[t] = d[t]; s[t + 256] = d[t + 256];
    __syncthreads();
    for (int off = 1; off < 512; off <<= 1) {
        int v0 = (t       >= off) ? s[t       - off] : 0;
        int v1 = (t + 256 >= off) ? s[t + 256 - off] : 0;
        __syncthreads();
        s[t] += v0; s[t + 256] += v1;
        __syncthreads();
    }
    int node0 = b * NPB;
    for (int l = t; l < NPB; l += 256) {
        int excl = s[l] - d[l];
        cur[l] = excl;
        int node = node0 + l;
        if (node < N_NODES) offsets[node] = gbase + excl;
    }
    __syncthreads();
    for (int i = t; i < n; i += 256) {
        int2 rec = tmp[(size_t)b * BCAP + i];
        int pos = atomicAdd(&cur[(rec.x >> 19) & 0x1FF], 1);
        frecs[gbase + pos] = make_int2(rec.x & 0x7FFFF, rec.y);
    }
}

// ---------------------------------------------------------------------------
// gatherb: wave per node over dense sorted recs; shfl-broadcast records;
// bf16 row reads (uint = 2 cols/lane); fp32 self term; shift-separated
// accumulators + single end rotation; 4-way unroll for MLP.
// ---------------------------------------------------------------------------
__global__ void gatherb_kernel(const float* __restrict__ x,
                               const ushort* __restrict__ xb,
                               const int* __restrict__ offsets,
                               const int2* __restrict__ recs,
                               const float* __restrict__ z0, const float* __restrict__ z1,
                               const float* __restrict__ z2, const float* __restrict__ z3,
                               float* __restrict__ out) {
    int wid  = (blockIdx.x * blockDim.x + threadIdx.x) >> 6;
    int lane = threadIdx.x & 63;
    if (wid >= N_NODES) return;

    float r0, r1, r2, r3;
    load_r(z0, z1, z2, z3, r0, r1, r2, r3);

    float2 xv = ((const float2*)(x + (size_t)wid * D))[lane];   // exact self term

    int beg = offsets[wid];
    int end = offsets[wid + 1];
    int count = end - beg;
    int cnt64 = (count < 64) ? count : 64;

    int2 myrec = make_int2(0, 0);
    if (lane < cnt64) myrec = recs[beg + lane];

    float2 a0 = {0.f, 0.f}, a1 = {0.f, 0.f}, a2 = {0.f, 0.f};

    int j = 0;
    for (; j + 3 < cnt64; j += 4) {
        int rxa = __shfl(myrec.x, j),     rya = __shfl(myrec.y, j);
        int rxb = __shfl(myrec.x, j + 1), ryb = __shfl(myrec.y, j + 1);
        int rxc = __shfl(myrec.x, j + 2), ryc = __shfl(myrec.y, j + 2);
        int rxd = __shfl(myrec.x, j + 3), ryd = __shfl(myrec.y, j + 3);
        unsigned int va = ((const unsigned int*)(xb + (size_t)(rxa & 0x1FFFF) * D))[lane];
        unsigned int vb = ((const unsigned int*)(xb + (size_t)(rxb & 0x1FFFF) * D))[lane];
        unsigned int vc = ((const unsigned int*)(xb + (size_t)(rxc & 0x1FFFF) * D))[lane];
        unsigned int vd = ((const unsigned int*)(xb + (size_t)(rxd & 0x1FFFF) * D))[lane];
        int sha = (rxa >> 17) & 3, shb = (rxb >> 17) & 3;
        int shc = (rxc >> 17) & 3, shd = (rxd >> 17) & 3;
        float sca = __int_as_float(rya), scb = __int_as_float(ryb);
        float scc = __int_as_float(ryc), scd = __int_as_float(ryd);
        float ax = __uint_as_float(va << 16), ay = __uint_as_float(va & 0xFFFF0000u);
        float bx = __uint_as_float(vb << 16), by = __uint_as_float(vb & 0xFFFF0000u);
        float cx = __uint_as_float(vc << 16), cy = __uint_as_float(vc & 0xFFFF0000u);
        float dx = __uint_as_float(vd << 16), dy = __uint_as_float(vd & 0xFFFF0000u);
        if      (sha == 0) { a0.x += sca * ax; a0.y += sca * ay; }
        else if (sha == 1) { a1.x += sca * ax; a1.y += sca * ay; }
        else               { a2.x += sca * ax; a2.y += sca * ay; }
        if      (shb == 0) { a0.x += scb * bx; a0.y += scb * by; }
        else if (shb == 1) { a1.x += scb * bx; a1.y += scb * by; }
        else               { a2.x += scb * bx; a2.y += scb * by; }
        if      (shc == 0) { a0.x += scc * cx; a0.y += scc * cy; }
        else if (shc == 1) { a1.x += scc * cx; a1.y += scc * cy; }
        else               { a2.x += scc * cx; a2.y += scc * cy; }
        if      (shd == 0) { a0.x += scd * dx; a0.y += scd * dy; }
        else if (shd == 1) { a1.x += scd * dx; a1.y += scd * dy; }
        else               { a2.x += scd * dx; a2.y += scd * dy; }
    }
    for (; j < cnt64; ++j) {
        int rx = __shfl(myrec.x, j), ry = __shfl(myrec.y, j);
        unsigned int vv = ((const unsigned int*)(xb + (size_t)(rx & 0x1FFFF) * D))[lane];
        int sh = (rx >> 17) & 3;
        float sc = __int_as_float(ry);
        float vx = __uint_as_float(vv << 16), vy = __uint_as_float(vv & 0xFFFF0000u);
        if      (sh == 0) { a0.x += sc * vx; a0.y += sc * vy; }
        else if (sh == 1) { a1.x += sc * vx; a1.y += sc * vy; }
        else               { a2.x += sc * vx; a2.y += sc * vy; }
    }
    for (int q = 64; q < count; ++q) {     // rare high-degree tail
        int2 rec = recs[beg + q];          // wave-uniform broadcast load
        unsigned int vv = ((const unsigned int*)(xb + (size_t)(rec.x & 0x1FFFF) * D))[lane];
        int sh = (rec.x >> 17) & 3;
        float sc = __int_as_float(rec.y);
        float vx = __uint_as_float(vv << 16), vy = __uint_as_float(vv & 0xFFFF0000u);
        if      (sh == 0) { a0.x += sc * vx; a0.y += sc * vy; }
        else if (sh == 1) { a1.x += sc * vx; a1.y += sc * vy; }
        else               { a2.x += sc * vx; a2.y += sc * vy; }
    }

    // out[c] = r0*x[c] + a0[c] + a1[(c-1)&127] + a2[(c-2)&127]
    int prev = (lane + 63) & 63;
    float r1y = __shfl(a1.y, prev);
    float r2x = __shfl(a2.x, prev);
    float r2y = __shfl(a2.y, prev);
    float2 o;
    o.x = r0 * xv.x + a0.x + r1y  + r2x;
    o.y = r0 * xv.y + a0.y + a1.x + r2y;
    ((float2*)(out + (size_t)wid * D))[lane] = o;
}

// overflow cleanup: wave per record, atomic add (expected ~0 records)
__global__ void ovf_kernel(const float* __restrict__ x,
                           const int* __restrict__ ovf_count,
                           const int4* __restrict__ ovf,
                           float* __restrict__ out) {
    int total_waves = (gridDim.x * blockDim.x) >> 6;
    int gw   = (blockIdx.x * blockDim.x + threadIdx.x) >> 6;
    int lane = threadIdx.x & 63;
    int n = *ovf_count;
    if (n > OVF_CAP) n = OVF_CAP;
    for (int r = gw; r < n; r += total_waves) {
        int4 rec = ovf[r];
        int src = rec.x;
        int dst = rec.y & 0x1FFFF;
        int sh  = (rec.y >> 17) & 3;
        float sc = __int_as_float(rec.z);
        const float* xr = x + (size_t)dst * D;
        float* orow = out + (size_t)src * D;
        int c0 = 2 * lane, c1 = 2 * lane + 1;
        atomicAdd(&orow[c0], sc * xr[(c0 - sh) & 127]);
        atomicAdd(&orow[c1], sc * xr[(c1 - sh) & 127]);
    }
}

// ===========================================================================
// MID TIER fallback (R3 exact-CSR path, fp32 gather), if ws too small.
// ===========================================================================
#define SCAN_BLOCKS ((N_NODES + 255) / 256)   // 391
#define WS_COUNTS   0
#define WS_OFFSETS  400000
#define WS_CURSORS  800008
#define WS_BSUM     1200008
#define WS_BPRE     1201576
#define WS_RECS     1203144
#define WS_NEEDED_MID (WS_RECS + (size_t)TOT_EDGES * 8)

__global__ void hist_kernel(const int* __restrict__ ei1, const int* __restrict__ ei2,
                            const int* __restrict__ ei3, int* __restrict__ counts) {
    int e = blockIdx.x * blockDim.x + threadIdx.x;
    if (e >= TOT_EDGES) return;
    int set = e / N_EDGES;
    int idx = e - set * N_EDGES;
    const int* ei = (set == 0) ? ei1 : (set == 1) ? ei2 : ei3;
    atomicAdd(&counts[ei[idx]], 1);
}

__global__ void scan1_kernel(const int* __restrict__ counts,
                             int* __restrict__ offsets, int* __restrict__ bsum) {
    __shared__ int s[256];
    int t = threadIdx.x;
    int i = blockIdx.x * 256 + t;
    int v = (i < N_NODES) ? counts[i] : 0;
    s[t] = v;
    __syncthreads();
    for (int off = 1; off < 256; off <<= 1) {
        int u = (t >= off) ? s[t - off] : 0;
        __syncthreads();
        s[t] += u;
        __syncthreads();
    }
    if (i < N_NODES) offsets[i] = s[t] - v;
    if (t == 255) bsum[blockIdx.x] = s[255];
}

__global__ void scan2_kernel(const int* __restrict__ bsum, int* __restrict__ bpre) {
    __shared__ int s[512];
    int t = threadIdx.x;
    int v = (t < SCAN_BLOCKS) ? bsum[t] : 0;
    s[t] = v;
    __syncthreads();
    for (int off = 1; off < 512; off <<= 1) {
        int u = (t >= off) ? s[t - off] : 0;
        __syncthreads();
        s[t] += u;
        __syncthreads();
    }
    if (t < SCAN_BLOCKS) bpre[t] = s[t] - v;
}

__global__ void scan3_kernel(int* __restrict__ offsets, const int* __restrict__ bpre,
                             int* __restrict__ cursors) {
    int i = blockIdx.x * 256 + threadIdx.x;
    if (i < N_NODES) {
        int v = offsets[i] + bpre[blockIdx.x];
        offsets[i] = v;
        cursors[i] = v;
    }
    if (i == 0) offsets[N_NODES] = TOT_EDGES;
}

__global__ void fill_kernel(const int* __restrict__ ei1, const float* __restrict__ w1,
                            const int* __restrict__ ei2, const float* __restrict__ w2,
                            const int* __restrict__ ei3, const float* __restrict__ w3,
                            const float* __restrict__ z0, const float* __restrict__ z1,
                            const float* __restrict__ z2, const float* __restrict__ z3,
                            int* __restrict__ cursors, int2* __restrict__ recs) {
    int e = blockIdx.x * blockDim.x + threadIdx.x;
    if (e >= TOT_EDGES) return;
    int set = e / N_EDGES;
    int idx = e - set * N_EDGES;
    const int* ei;  const float* w;
    if      (set == 0) { ei = ei1; w = w1; }
    else if (set == 1) { ei = ei2; w = w2; }
    else               { ei = ei3; w = w3; }
    float r0, r1, r2, r3;
    load_r(z0, z1, z2, z3, r0, r1, r2, r3);
    float rk = (set == 0) ? r1 : (set == 1) ? r2 : r3;
    int src = ei[idx];
    int dst = ei[N_EDGES + idx];
    float scale = rk * w[idx];
    int pos = atomicAdd(&cursors[src], 1);
    recs[pos] = make_int2(dst | (set << 17), __float_as_int(scale));
}

__global__ void gatherd_kernel(const float* __restrict__ x,
                               const int* __restrict__ offsets,
                               const int2* __restrict__ recs,
                               const float* __restrict__ z0, const float* __restrict__ z1,
                               const float* __restrict__ z2, const float* __restrict__ z3,
                               float* __restrict__ out) {
    int wid  = (blockIdx.x * blockDim.x + threadIdx.x) >> 6;
    int lane = threadIdx.x & 63;
    if (wid >= N_NODES) return;
    float r0, r1, r2, r3;
    load_r(z0, z1, z2, z3, r0, r1, r2, r3);
    float2 xv = ((const float2*)(x + (size_t)wid * D))[lane];
    int beg = offsets[wid];
    int end = offsets[wid + 1];
    float2 a0 = {0.f, 0.f}, a1 = {0.f, 0.f}, a2 = {0.f, 0.f};
    for (int j = beg; j < end; ++j) {
        int2 rec = recs[j];
        float2 v = ((const float2*)(x + (size_t)(rec.x & 0x1FFFF) * D))[lane];
        int sh = (rec.x >> 17) & 3;
        float sc = __int_as_float(rec.y);
        if      (sh == 0) { a0.x += sc * v.x; a0.y += sc * v.y; }
        else if (sh == 1) { a1.x += sc * v.x; a1.y += sc * v.y; }
        else               { a2.x += sc * v.x; a2.y += sc * v.y; }
    }
    int prev = (lane + 63) & 63;
    float r1y = __shfl(a1.y, prev);
    float r2x = __shfl(a2.x, prev);
    float r2y = __shfl(a2.y, prev);
    float2 o;
    o.x = r0 * xv.x + a0.x + r1y  + r2x;
    o.y = r0 * xv.y + a0.y + a1.x + r2y;
    ((float2*)(out + (size_t)wid * D))[lane] = o;
}

extern "C" void kernel_launch(void* const* d_in, const int* in_sizes, int n_in,
                              void* d_out, int out_size, void* d_ws, size_t ws_size,
                              hipStream_t stream) {
    const float* x   = (const float*)d_in[0];
    const int*   ei1 = (const int*)  d_in[1];
    const float* w1  = (const float*)d_in[2];
    const int*   ei2 = (const int*)  d_in[3];
    const float* w2  = (const float*)d_in[4];
    const int*   ei3 = (const int*)  d_in[5];
    const float* w3  = (const float*)d_in[6];
    const float* z0  = (const float*)d_in[7];
    const float* z1  = (const float*)d_in[8];
    const float* z2  = (const float*)d_in[9];
    const float* z3  = (const float*)d_in[10];
    float* out = (float*)d_out;
    char* wsc = (char*)d_ws;

    if (ws_size >= WS_TOTAL_FAST) {
        int*    ovf_count = (int*)   (wsc + WS_OVFCNT);
        int*    bcur      = (int*)   (wsc + WS_BCUR);
        int*    bbase     = (int*)   (wsc + WS_BBASE);
        int*    bnum      = (int*)   (wsc + WS_BNUM);
        int4*   ovf       = (int4*)  (wsc + WS_OVF);
        int2*   tmp       = (int2*)  (wsc + WS_TMP);
        int2*   frecs     = (int2*)  (wsc + WS_FREC);
        int*    offsets   = (int*)   (wsc + WS_OFFS);
        ushort* xb        = (ushort*)(wsc + WS_XB);

        hipMemsetAsync(wsc, 0, WS_BBASE, stream);   // ovf_count + bucket cursors
        cast_kernel<<<(N_NODES * D / 4 + 255) / 256, 256, 0, stream>>>(x, xb);
        binA_kernel<<<BINA_BLOCKS, 256, 0, stream>>>(ei1, w1, ei2, w2, ei3, w3,
                                                     z0, z1, z2, z3,
                                                     bcur, ovf_count, ovf, tmp);
        scanB_kernel<<<1, NB, 0, stream>>>(bcur, bbase, bnum, offsets);
        binB_kernel<<<NB, 256, 0, stream>>>(tmp, bbase, bnum, frecs, offsets);
        gatherb_kernel<<<(N_NODES * 64 + 255) / 256, 256, 0, stream>>>(x, xb, offsets,
                                                                       frecs, z0, z1, z2, z3,
                                                                       out);
        ovf_kernel<<<128, 256, 0, stream>>>(x, ovf_count, ovf, out);
    } else {
        int*  counts  = (int*) (wsc + WS_COUNTS);
        int*  offsets = (int*) (wsc + WS_OFFSETS);
        int*  cursors = (int*) (wsc + WS_CURSORS);
        int*  bsum    = (int*) (wsc + WS_BSUM);
        int*  bpre    = (int*) (wsc + WS_BPRE);
        int2* recs    = (int2*)(wsc + WS_RECS);

        hipMemsetAsync(counts, 0, N_NODES * sizeof(int), stream);
        hist_kernel<<<TOT_EDGES / 256, 256, 0, stream>>>(ei1, ei2, ei3, counts);
        scan1_kernel<<<SCAN_BLOCKS, 256, 0, stream>>>(counts, offsets, bsum);
        scan2_kernel<<<1, 512, 0, stream>>>(bsum, bpre);
        scan3_kernel<<<SCAN_BLOCKS, 256, 0, stream>>>(offsets, bpre, cursors);
        fill_kernel<<<TOT_EDGES / 256, 256, 0, stream>>>(ei1, w1, ei2, w2, ei3, w3,
                                                         z0, z1, z2, z3, cursors, recs);
        gatherd_kernel<<<(N_NODES * 64 + 255) / 256, 256, 0, stream>>>(x, offsets, recs,
                                                                       z0, z1, z2, z3, out);
    }
}